// Round 1
// baseline (42.230 us; speedup 1.0000x reference)
//
#include <hip/hip_runtime.h>

// Reference: for i in range(1000): x = 1.0 * x  -> identity.
// Output = input, float32, 4096*8192 elements. Pure D2D copy.
//
// hipMemcpyAsync(d2d, stream) is graph-capture-safe and reaches ~85% of
// HBM peak on MI355X — use it directly.

extern "C" void kernel_launch(void* const* d_in, const int* in_sizes, int n_in,
                              void* d_out, int out_size, void* d_ws, size_t ws_size,
                              hipStream_t stream) {
    const float* x = (const float*)d_in[0];
    float* out = (float*)d_out;
    size_t nbytes = (size_t)out_size * sizeof(float);
    hipMemcpyAsync(out, x, nbytes, hipMemcpyDeviceToDevice, stream);
}